// Round 3
// baseline (142.120 us; speedup 1.0000x reference)
//
#include <hip/hip_runtime.h>
#include <math.h>

// 18-qubit statevector, 2 circuits + |<psi2|psi1>|^2.
// Qubit q (reference) <-> index bit (17-q). CZ chain diagonal:
// sign = parity(popc(i & (i>>1) & 0x1FFFF)).
//
// 7 passes, local sets A={0..9} / B={0,1}u{10..17}, 1024-amp chunks,
// 512 blocks x 256 thr (2 blocks/CU -> 2 waves/SIMD). Per pass, each thread
// holds 4 amps; gates on local bits 0..5 are __shfl_xor butterflies (no
// LDS, no barrier), bits held in the reg index are free, and the two
// remaining bits are rotated into the reg index by one LDS re-permute each
// way (3 barriers/pass total). CZ folded in registers. Final pass fuses the
// layer-5 leftover + CZ5 + overlap reduction for both circuits.

#define NQ      18
#define NSTATE  (1 << NQ)
#define LAYERS  6
#define SLOC    10
#define NL      (1 << SLOC)      // 1024 amps per chunk
#define TPB     256
#define NCHUNK  (NSTATE / NL)    // 256 chunks per circuit

// ---------------- setup: compose U = RZ*RY*RX per (circuit, layer, qubit) ---
__global__ __launch_bounds__(256) void setup_kernel(
    const float* __restrict__ x1, const float* __restrict__ x2,
    const float* __restrict__ iscale, const float* __restrict__ var,
    float2* __restrict__ U, double* __restrict__ acc, unsigned* __restrict__ cnt)
{
    int tid = threadIdx.x;
    if (tid == 0) { acc[0] = 0.0; acc[1] = 0.0; *cnt = 0u; }
    if (tid >= 2 * LAYERS * NQ) return;
    int c = tid / (LAYERS * NQ);
    int rem = tid % (LAYERS * NQ);
    int l = rem / NQ, q = rem % NQ;
    const float* x = c ? x2 : x1;
    double tx = (double)iscale[l * NQ + q] * (double)x[q];
    double ty = (double)var[l * 2 * NQ + q];
    double tz = (double)var[l * 2 * NQ + NQ + q];
    double cx = cos(tx * 0.5), sx = sin(tx * 0.5);
    double cy = cos(ty * 0.5), sy = sin(ty * 0.5);
    double m00r = cy * cx,  m00i =  sy * sx;
    double m01r = -sy * cx, m01i = -cy * sx;
    double m10r = sy * cx,  m10i = -cy * sx;
    double m11r = cy * cx,  m11i = -sy * sx;
    double zc = cos(tz * 0.5), zs = sin(tz * 0.5);
    double u00r = m00r * zc + m00i * zs, u00i = m00i * zc - m00r * zs;
    double u01r = m01r * zc + m01i * zs, u01i = m01i * zc - m01r * zs;
    double u10r = m10r * zc - m10i * zs, u10i = m10i * zc + m10r * zs;
    double u11r = m11r * zc - m11i * zs, u11i = m11i * zc + m11r * zs;
    float2* up = U + tid * 4;
    up[0] = make_float2((float)u00r, (float)u00i);
    up[1] = make_float2((float)u01r, (float)u01i);
    up[2] = make_float2((float)u10r, (float)u10i);
    up[3] = make_float2((float)u11r, (float)u11i);
}

// ---------------- gate helpers ----------------------------------------------
__device__ __forceinline__ void cpair(
    float& a0r, float& a0i, float& a1r, float& a1i,
    float u00r, float u00i, float u01r, float u01i,
    float u10r, float u10i, float u11r, float u11i)
{
    float n0r = u00r * a0r - u00i * a0i + u01r * a1r - u01i * a1i;
    float n0i = u00r * a0i + u00i * a0r + u01r * a1i + u01i * a1r;
    float n1r = u10r * a0r - u10i * a0i + u11r * a1r - u11i * a1i;
    float n1i = u10r * a0i + u10i * a0r + u11r * a1i + u11i * a1r;
    a0r = n0r; a0i = n0i; a1r = n1r; a1i = n1i;
}

// gate on a bit held in the per-thread amp index (RB = 1 or 2)
template<int RB>
__device__ __forceinline__ void reg_gate(float (&ar)[4], float (&ai)[4],
                                         const float2* __restrict__ up)
{
    float u00r = up[0].x, u00i = up[0].y, u01r = up[1].x, u01i = up[1].y;
    float u10r = up[2].x, u10i = up[2].y, u11r = up[3].x, u11i = up[3].y;
#pragma unroll
    for (int r = 0; r < 4; ++r) {
        if (r & RB) continue;
        int r1 = r | RB;
        cpair(ar[r], ai[r], ar[r1], ai[r1],
              u00r, u00i, u01r, u01i, u10r, u10i, u11r, u11i);
    }
}

// gate on a lane bit j (0..5): cross-lane butterfly via shfl_xor, no barrier
__device__ __forceinline__ void lane_gate(float (&ar)[4], float (&ai)[4],
                                          const float2* __restrict__ up,
                                          int lane, int j)
{
    float u00r = up[0].x, u00i = up[0].y, u01r = up[1].x, u01i = up[1].y;
    float u10r = up[2].x, u10i = up[2].y, u11r = up[3].x, u11i = up[3].y;
    int side = (lane >> j) & 1;
    float car = side ? u11r : u00r, cai = side ? u11i : u00i;
    float cbr = side ? u10r : u01r, cbi = side ? u10i : u01i;
#pragma unroll
    for (int r = 0; r < 4; ++r) {
        float pr = __shfl_xor(ar[r], 1 << j, 64);
        float pi = __shfl_xor(ai[r], 1 << j, 64);
        float mr = ar[r], mi = ai[r];
        ar[r] = car * mr - cai * mi + cbr * pr - cbi * pi;
        ai[r] = car * mi + cai * mr + cbr * pi + cbi * pr;
    }
}

__device__ __forceinline__ int gidx_f(int L, int g, int setB)
{
    return setB ? (((L >> 2) << 10) | (g << 2) | (L & 3)) : ((g << 10) | L);
}

__device__ __forceinline__ int cz_neg(int gi)
{
    return __popc(gi & (gi >> 1) & 0x1FFFF) & 1;
}

// ---------------- one pass (P0..P5) ----------------------------------------
__global__ __launch_bounds__(TPB) void pass_kernel(
    float2* __restrict__ states, const float2* __restrict__ U,
    int setB, int pl, int do_cz, int nl, int do_init)
{
    __shared__ float sre[NL];
    __shared__ float sim[NL];
    int blk = blockIdx.x;
    int circ = blk >> 8;
    int g = blk & (NCHUNK - 1);
    int t = threadIdx.x, lane = t & 63, wave = t >> 6;
    float2* st = states + (size_t)circ * NSTATE;
    const float2* Ub = U + (size_t)circ * (LAYERS * NQ * 4);

    // gate-matrix for local bit s of layer `layer`
    auto gp = [&](int layer, int s) -> const float2* {
        int gb = setB ? (s < 2 ? s : s + 8) : s;
        return Ub + ((size_t)layer * NQ + (17 - gb)) * 4;
    };

    int Lm1[4], Lm2[4];
#pragma unroll
    for (int r = 0; r < 4; ++r) {
        Lm1[r] = (r << 8) | (wave << 6) | lane;   // M1: reg bits = local 8,9
        Lm2[r] = (wave << 8) | (r << 6) | lane;   // M2: reg bits = local 6,7
    }

    float ar[4], ai[4];
    if (do_init) {
#pragma unroll
        for (int r = 0; r < 4; ++r) {
            ar[r] = (g == 0 && Lm1[r] == 0) ? 1.0f : 0.0f;
            ai[r] = 0.0f;
        }
    } else {
#pragma unroll
        for (int r = 0; r < 4; ++r) {
            float2 v = st[gidx_f(Lm1[r], g, setB)];
            ar[r] = v.x; ai[r] = v.y;
        }
    }

    // phase 1 (M1): prev-layer gates on local 2..5 (lane) and 8,9 (reg)
    if (pl >= 0) {
        lane_gate(ar, ai, gp(pl, 2), lane, 2);
        lane_gate(ar, ai, gp(pl, 3), lane, 3);
        lane_gate(ar, ai, gp(pl, 4), lane, 4);
        lane_gate(ar, ai, gp(pl, 5), lane, 5);
        reg_gate<1>(ar, ai, gp(pl, 8));
        reg_gate<2>(ar, ai, gp(pl, 9));
    }

    // re-permute M1 -> M2
#pragma unroll
    for (int r = 0; r < 4; ++r) { sre[Lm1[r]] = ar[r]; sim[Lm1[r]] = ai[r]; }
    __syncthreads();
#pragma unroll
    for (int r = 0; r < 4; ++r) { ar[r] = sre[Lm2[r]]; ai[r] = sim[Lm2[r]]; }

    // phase 2 (M2): prev gates 6,7 (reg); CZ; next gates 0..5 (lane), 6,7 (reg)
    if (pl >= 0) {
        reg_gate<1>(ar, ai, gp(pl, 6));
        reg_gate<2>(ar, ai, gp(pl, 7));
    }
    if (do_cz) {
#pragma unroll
        for (int r = 0; r < 4; ++r) {
            if (cz_neg(gidx_f(Lm2[r], g, setB))) { ar[r] = -ar[r]; ai[r] = -ai[r]; }
        }
    }
    if (nl >= 0) {
        lane_gate(ar, ai, gp(nl, 0), lane, 0);
        lane_gate(ar, ai, gp(nl, 1), lane, 1);
        lane_gate(ar, ai, gp(nl, 2), lane, 2);
        lane_gate(ar, ai, gp(nl, 3), lane, 3);
        lane_gate(ar, ai, gp(nl, 4), lane, 4);
        lane_gate(ar, ai, gp(nl, 5), lane, 5);
        reg_gate<1>(ar, ai, gp(nl, 6));
        reg_gate<2>(ar, ai, gp(nl, 7));
    }

    // re-permute M2 -> M1
    __syncthreads();   // all phase-2 reads done before rewrite
#pragma unroll
    for (int r = 0; r < 4; ++r) { sre[Lm2[r]] = ar[r]; sim[Lm2[r]] = ai[r]; }
    __syncthreads();
#pragma unroll
    for (int r = 0; r < 4; ++r) { ar[r] = sre[Lm1[r]]; ai[r] = sim[Lm1[r]]; }

    // phase 3 (M1): next gates 8,9 (reg), store
    if (nl >= 0) {
        reg_gate<1>(ar, ai, gp(nl, 8));
        reg_gate<2>(ar, ai, gp(nl, 9));
    }
#pragma unroll
    for (int r = 0; r < 4; ++r)
        st[gidx_f(Lm1[r], g, setB)] = make_float2(ar[r], ai[r]);
}

// ---------------- final pass: layer-5 leftover + CZ5 + overlap --------------
__global__ __launch_bounds__(TPB) void final_kernel(
    const float2* __restrict__ states, const float2* __restrict__ U,
    double* __restrict__ acc, unsigned* __restrict__ cnt,
    float* __restrict__ out)
{
    __shared__ float sre[NL];
    __shared__ float sim[NL];
    __shared__ double wr[4], wi[4];
    int g = blockIdx.x;
    int t = threadIdx.x, lane = t & 63, wave = t >> 6;

    int Lm1[4], Lm2[4];
#pragma unroll
    for (int r = 0; r < 4; ++r) {
        Lm1[r] = (r << 8) | (wave << 6) | lane;
        Lm2[r] = (wave << 8) | (r << 6) | lane;
    }

    double accr = 0.0, acci = 0.0;
    float p1r[4], p1i[4];

    for (int c = 0; c < 2; ++c) {
        const float2* st = states + (size_t)c * NSTATE;
        const float2* Ub = U + (size_t)c * (LAYERS * NQ * 4);
        auto gp = [&](int s) -> const float2* {   // set A, layer 5
            return Ub + ((size_t)5 * NQ + (17 - s)) * 4;
        };
        float ar[4], ai[4];
#pragma unroll
        for (int r = 0; r < 4; ++r) {
            float2 v = st[(g << 10) | Lm1[r]];
            ar[r] = v.x; ai[r] = v.y;
        }
        // phase 1 (M1): layer-5 leftover on local 2..5 (lane), 8,9 (reg)
        lane_gate(ar, ai, gp(2), lane, 2);
        lane_gate(ar, ai, gp(3), lane, 3);
        lane_gate(ar, ai, gp(4), lane, 4);
        lane_gate(ar, ai, gp(5), lane, 5);
        reg_gate<1>(ar, ai, gp(8));
        reg_gate<2>(ar, ai, gp(9));
        // re-permute M1 -> M2 (protect previous circuit's reads first)
        __syncthreads();
#pragma unroll
        for (int r = 0; r < 4; ++r) { sre[Lm1[r]] = ar[r]; sim[Lm1[r]] = ai[r]; }
        __syncthreads();
#pragma unroll
        for (int r = 0; r < 4; ++r) { ar[r] = sre[Lm2[r]]; ai[r] = sim[Lm2[r]]; }
        // phase 2 (M2): gates 6,7 (reg), CZ5
        reg_gate<1>(ar, ai, gp(6));
        reg_gate<2>(ar, ai, gp(7));
#pragma unroll
        for (int r = 0; r < 4; ++r) {
            if (cz_neg((g << 10) | Lm2[r])) { ar[r] = -ar[r]; ai[r] = -ai[r]; }
        }
        if (c == 0) {
#pragma unroll
            for (int r = 0; r < 4; ++r) { p1r[r] = ar[r]; p1i[r] = ai[r]; }
        } else {
#pragma unroll
            for (int r = 0; r < 4; ++r) {
                // conj(psi2) * psi1
                accr += (double)ar[r] * p1r[r] + (double)ai[r] * p1i[r];
                acci += (double)ar[r] * p1i[r] - (double)ai[r] * p1r[r];
            }
        }
    }

    for (int o = 32; o > 0; o >>= 1) {
        accr += __shfl_down(accr, o, 64);
        acci += __shfl_down(acci, o, 64);
    }
    if (lane == 0) { wr[wave] = accr; wi[wave] = acci; }
    __syncthreads();
    if (t == 0) {
        double br = wr[0] + wr[1] + wr[2] + wr[3];
        double bi = wi[0] + wi[1] + wi[2] + wi[3];
        atomicAdd(&acc[0], br);
        atomicAdd(&acc[1], bi);
        __threadfence();
        unsigned old = atomicAdd(cnt, 1u);
        if (old == gridDim.x - 1) {
            double fr = atomicAdd(&acc[0], 0.0);
            double fi = atomicAdd(&acc[1], 0.0);
            out[0] = (float)(fr * fr + fi * fi);
        }
    }
}

// ---------------- launch ----------------------------------------------------
extern "C" void kernel_launch(void* const* d_in, const int* in_sizes, int n_in,
                              void* d_out, int out_size, void* d_ws, size_t ws_size,
                              hipStream_t stream)
{
    const float* x1 = (const float*)d_in[0];
    const float* x2 = (const float*)d_in[1];
    const float* iscale = (const float*)d_in[2];
    const float* var = (const float*)d_in[3];
    float* out = (float*)d_out;

    // ws layout: [0,6912) U; [8192,8208) acc; [8208,8212) cnt;
    // [16384, 16384+4MB) statevectors.
    float2*   U      = (float2*)d_ws;
    double*   acc    = (double*)((char*)d_ws + 8192);
    unsigned* cnt    = (unsigned*)((char*)d_ws + 8208);
    float2*   states = (float2*)((char*)d_ws + 16384);

    setup_kernel<<<1, 256, 0, stream>>>(x1, x2, iscale, var, U, acc, cnt);

    dim3 grid(2 * NCHUNK), block(TPB);
    // args: setB, prev_layer, do_cz, next_layer, do_init
    pass_kernel<<<grid, block, 0, stream>>>(states, U, 0, -1, 0, 0, 1);
    pass_kernel<<<grid, block, 0, stream>>>(states, U, 1, 0, 1, 1, 0);
    pass_kernel<<<grid, block, 0, stream>>>(states, U, 0, 1, 1, 2, 0);
    pass_kernel<<<grid, block, 0, stream>>>(states, U, 1, 2, 1, 3, 0);
    pass_kernel<<<grid, block, 0, stream>>>(states, U, 0, 3, 1, 4, 0);
    pass_kernel<<<grid, block, 0, stream>>>(states, U, 1, 4, 1, 5, 0);
    final_kernel<<<NCHUNK, block, 0, stream>>>(states, U, acc, cnt, out);
}

// Round 4
// 118.062 us; speedup vs baseline: 1.2038x; 1.2038x over previous
//
#include <hip/hip_runtime.h>
#include <math.h>

// 18-qubit statevector, 2 circuits + |<psi2|psi1>|^2, 6 kernels total.
// Qubit q (reference) <-> index bit (17-q). CZ chain diagonal:
// sign = parity(popc(i & (i>>1) & 0x1FFFF)).
//
// K1: layer-0 state is a PRODUCT state (closed form, no loads) + CZ0 +
//     layer-1 gates on set B.
// K2..K5: leftover gates + CZ + next-layer gates (sets A,B,A,B).
// K6: layer-5 leftover collapses to 8 combined RX(th1-th2) gates on psi1
//     (RZ*RY and CZ5 are circuit-independent -> cancel in the overlap);
//     dot against raw psi2.
// All kernels compose their own fused U = RZ*RY*RX in fp64 via 54-thread
// sincos into LDS (no setup kernel). Sets: A={0..9}, B={0,1}u{10..17};
// 1024-amp chunks, 512 blocks x 256 thr (2 blocks/CU). Per thread 4 amps;
// lane bits 0..5 via shfl_xor, reg bits via 2 LDS rotations (M1: reg={8,9},
// M2: reg={6,7}).

#define NQ      18
#define NSTATE  (1 << NQ)
#define LAYERS  6
#define SLOC    10
#define NL      (1 << SLOC)
#define TPB     256
#define NCHUNK  (NSTATE / NL)    // 256 chunks per circuit

__device__ __forceinline__ float2 cmulf(float2 a, float2 b) {
    return make_float2(a.x * b.x - a.y * b.y, a.x * b.y + a.y * b.x);
}

__device__ __forceinline__ void compose_U(double cx, double sx, double cy,
                                          double sy, double zc, double zs,
                                          float2* up)
{
    double m00r = cy * cx,  m00i =  sy * sx;
    double m01r = -sy * cx, m01i = -cy * sx;
    double m10r = sy * cx,  m10i = -cy * sx;
    double m11r = cy * cx,  m11i = -sy * sx;
    up[0] = make_float2((float)(m00r * zc + m00i * zs), (float)(m00i * zc - m00r * zs));
    up[1] = make_float2((float)(m01r * zc + m01i * zs), (float)(m01i * zc - m01r * zs));
    up[2] = make_float2((float)(m10r * zc - m10i * zs), (float)(m10i * zc + m10r * zs));
    up[3] = make_float2((float)(m11r * zc - m11i * zs), (float)(m11i * zc + m11r * zs));
}

__device__ __forceinline__ void cpair(
    float& a0r, float& a0i, float& a1r, float& a1i,
    float u00r, float u00i, float u01r, float u01i,
    float u10r, float u10i, float u11r, float u11i)
{
    float n0r = u00r * a0r - u00i * a0i + u01r * a1r - u01i * a1i;
    float n0i = u00r * a0i + u00i * a0r + u01r * a1i + u01i * a1r;
    float n1r = u10r * a0r - u10i * a0i + u11r * a1r - u11i * a1i;
    float n1i = u10r * a0i + u10i * a0r + u11r * a1i + u11i * a1r;
    a0r = n0r; a0i = n0i; a1r = n1r; a1i = n1i;
}

template<int RB>
__device__ __forceinline__ void reg_gate(float (&ar)[4], float (&ai)[4],
                                         const float2* up)
{
    float u00r = up[0].x, u00i = up[0].y, u01r = up[1].x, u01i = up[1].y;
    float u10r = up[2].x, u10i = up[2].y, u11r = up[3].x, u11i = up[3].y;
#pragma unroll
    for (int r = 0; r < 4; ++r) {
        if (r & RB) continue;
        int r1 = r | RB;
        cpair(ar[r], ai[r], ar[r1], ai[r1],
              u00r, u00i, u01r, u01i, u10r, u10i, u11r, u11i);
    }
}

__device__ __forceinline__ void lane_gate(float (&ar)[4], float (&ai)[4],
                                          const float2* up, int lane, int j)
{
    float u00r = up[0].x, u00i = up[0].y, u01r = up[1].x, u01i = up[1].y;
    float u10r = up[2].x, u10i = up[2].y, u11r = up[3].x, u11i = up[3].y;
    int side = (lane >> j) & 1;
    float car = side ? u11r : u00r, cai = side ? u11i : u00i;
    float cbr = side ? u10r : u01r, cbi = side ? u10i : u01i;
#pragma unroll
    for (int r = 0; r < 4; ++r) {
        float pr = __shfl_xor(ar[r], 1 << j, 64);
        float pi = __shfl_xor(ai[r], 1 << j, 64);
        float mr = ar[r], mi = ai[r];
        ar[r] = car * mr - cai * mi + cbr * pr - cbi * pi;
        ai[r] = car * mi + cai * mr + cbr * pi + cbi * pr;
    }
}

__device__ __forceinline__ int gidx_f(int L, int g, int setB)
{
    return setB ? (((L >> 2) << 10) | (g << 2) | (L & 3)) : ((g << 10) | L);
}

__device__ __forceinline__ int cz_neg(int gi)
{
    return __popc(gi & (gi >> 1) & 0x1FFFF) & 1;
}

// ---------------- K1: product state + CZ0 + layer-1 on set B ---------------
__global__ __launch_bounds__(TPB) void k1_kernel(
    float2* __restrict__ states,
    const float* __restrict__ x1, const float* __restrict__ x2,
    const float* __restrict__ iscale, const float* __restrict__ var,
    double* __restrict__ acc, unsigned* __restrict__ cnt)
{
    __shared__ double2 ssc[84];
    __shared__ float2 sU[28][4];   // 0..17: layer-0 U per bit b; 18..27: layer-1, local bits 0..9
    __shared__ float sre[NL], sim[NL];
    int blk = blockIdx.x;
    int circ = blk >> 8;
    int g = blk & (NCHUNK - 1);
    int t = threadIdx.x, lane = t & 63, wave = t >> 6;
    float2* st = states + (size_t)circ * NSTATE;
    if (blk == 0 && t == 0) { acc[0] = 0.0; acc[1] = 0.0; *cnt = 0u; }

    const float* xv = circ ? x2 : x1;
    if (t < 84) {
        int gs = t / 3, c = t % 3;
        int layer, q;
        if (gs < 18) { layer = 0; q = 17 - gs; }
        else { int lb = gs - 18; int gb = lb < 2 ? lb : lb + 8; layer = 1; q = 17 - gb; }
        double ang = (c == 0) ? (double)iscale[layer * NQ + q] * (double)xv[q]
                   : (c == 1) ? (double)var[layer * 2 * NQ + q]
                              : (double)var[layer * 2 * NQ + NQ + q];
        double sn, cs;
        sincos(ang * 0.5, &sn, &cs);
        ssc[t] = make_double2(cs, sn);
    }
    __syncthreads();
    if (t < 28)
        compose_U(ssc[3 * t].x, ssc[3 * t].y, ssc[3 * t + 1].x, ssc[3 * t + 1].y,
                  ssc[3 * t + 2].x, ssc[3 * t + 2].y, sU[t]);
    __syncthreads();

    int Lm1[4], Lm2[4];
#pragma unroll
    for (int r = 0; r < 4; ++r) {
        Lm1[r] = (r << 8) | (wave << 6) | lane;
        Lm2[r] = (wave << 8) | (r << 6) | lane;
    }

    // product state in M2 layout (v[b][bit] = bit ? sU[b][2] : sU[b][0])
    float2 com = make_float2(1.f, 0.f);
#pragma unroll
    for (int b = 2; b <= 9; ++b) {           // global bits 2..9 from g
        int bit = (g >> (b - 2)) & 1;
        com = cmulf(com, bit ? sU[b][2] : sU[b][0]);
    }
#pragma unroll
    for (int k = 0; k < 6; ++k) {            // lane = local 0..5 -> global {0,1,10..13}
        int gb = k < 2 ? k : k + 8;
        int bit = (lane >> k) & 1;
        com = cmulf(com, bit ? sU[gb][2] : sU[gb][0]);
    }
    com = cmulf(com, (wave & 1) ? sU[16][2] : sU[16][0]);        // local 8 -> g16
    com = cmulf(com, ((wave >> 1) & 1) ? sU[17][2] : sU[17][0]); // local 9 -> g17

    float ar[4], ai[4];
#pragma unroll
    for (int r = 0; r < 4; ++r) {            // local 6,7 -> global 14,15
        float2 rf = cmulf((r & 1) ? sU[14][2] : sU[14][0],
                          ((r >> 1) & 1) ? sU[15][2] : sU[15][0]);
        float2 a = cmulf(com, rf);
        ar[r] = a.x; ai[r] = a.y;
    }
    // CZ0
#pragma unroll
    for (int r = 0; r < 4; ++r)
        if (cz_neg(gidx_f(Lm2[r], g, 1))) { ar[r] = -ar[r]; ai[r] = -ai[r]; }
    // layer-1 gates on B: lane 0..5 (slots 18..23), reg 6,7 (slots 24,25)
    lane_gate(ar, ai, sU[18], lane, 0);
    lane_gate(ar, ai, sU[19], lane, 1);
    lane_gate(ar, ai, sU[20], lane, 2);
    lane_gate(ar, ai, sU[21], lane, 3);
    lane_gate(ar, ai, sU[22], lane, 4);
    lane_gate(ar, ai, sU[23], lane, 5);
    reg_gate<1>(ar, ai, sU[24]);
    reg_gate<2>(ar, ai, sU[25]);
    // rotate M2 -> M1
#pragma unroll
    for (int r = 0; r < 4; ++r) { sre[Lm2[r]] = ar[r]; sim[Lm2[r]] = ai[r]; }
    __syncthreads();
#pragma unroll
    for (int r = 0; r < 4; ++r) { ar[r] = sre[Lm1[r]]; ai[r] = sim[Lm1[r]]; }
    // layer-1 reg 8,9 (slots 26,27), store
    reg_gate<1>(ar, ai, sU[26]);
    reg_gate<2>(ar, ai, sU[27]);
#pragma unroll
    for (int r = 0; r < 4; ++r)
        st[gidx_f(Lm1[r], g, 1)] = make_float2(ar[r], ai[r]);
}

// ---------------- K2..K5: leftover(pl) + CZ(pl) + layer(nl) on set --------
__global__ __launch_bounds__(TPB) void pass_kernel(
    float2* __restrict__ states,
    const float* __restrict__ x1, const float* __restrict__ x2,
    const float* __restrict__ iscale, const float* __restrict__ var,
    int setB, int pl, int nl)
{
    __shared__ double2 ssc[54];
    __shared__ float2 sU[18][4];  // 0..7: prev, local bits 2..9; 8..17: next, local 0..9
    __shared__ float sre[NL], sim[NL];
    int blk = blockIdx.x;
    int circ = blk >> 8;
    int g = blk & (NCHUNK - 1);
    int t = threadIdx.x, lane = t & 63, wave = t >> 6;
    float2* st = states + (size_t)circ * NSTATE;

    int Lm1[4], Lm2[4];
#pragma unroll
    for (int r = 0; r < 4; ++r) {
        Lm1[r] = (r << 8) | (wave << 6) | lane;
        Lm2[r] = (wave << 8) | (r << 6) | lane;
    }
    // issue global loads early; they drain during U composition
    float2 v4[4];
#pragma unroll
    for (int r = 0; r < 4; ++r) v4[r] = st[gidx_f(Lm1[r], g, setB)];

    const float* xv = circ ? x2 : x1;
    if (t < 54) {
        int gs = t / 3, c = t % 3;
        int layer, lbit;
        if (gs < 8) { layer = pl; lbit = 2 + gs; }
        else        { layer = nl; lbit = gs - 8; }
        int gb = setB ? (lbit < 2 ? lbit : lbit + 8) : lbit;
        int q = 17 - gb;
        double ang = (c == 0) ? (double)iscale[layer * NQ + q] * (double)xv[q]
                   : (c == 1) ? (double)var[layer * 2 * NQ + q]
                              : (double)var[layer * 2 * NQ + NQ + q];
        double sn, cs;
        sincos(ang * 0.5, &sn, &cs);
        ssc[t] = make_double2(cs, sn);
    }
    __syncthreads();
    if (t < 18)
        compose_U(ssc[3 * t].x, ssc[3 * t].y, ssc[3 * t + 1].x, ssc[3 * t + 1].y,
                  ssc[3 * t + 2].x, ssc[3 * t + 2].y, sU[t]);
    __syncthreads();

    float ar[4], ai[4];
#pragma unroll
    for (int r = 0; r < 4; ++r) { ar[r] = v4[r].x; ai[r] = v4[r].y; }

    // phase 1 (M1): prev gates lane 2..5 (slots 0..3), reg 8,9 (slots 6,7)
    lane_gate(ar, ai, sU[0], lane, 2);
    lane_gate(ar, ai, sU[1], lane, 3);
    lane_gate(ar, ai, sU[2], lane, 4);
    lane_gate(ar, ai, sU[3], lane, 5);
    reg_gate<1>(ar, ai, sU[6]);
    reg_gate<2>(ar, ai, sU[7]);
    // rotate M1 -> M2 (slots thread-exclusive: write/read pattern needs 1 barrier)
#pragma unroll
    for (int r = 0; r < 4; ++r) { sre[Lm1[r]] = ar[r]; sim[Lm1[r]] = ai[r]; }
    __syncthreads();
#pragma unroll
    for (int r = 0; r < 4; ++r) { ar[r] = sre[Lm2[r]]; ai[r] = sim[Lm2[r]]; }
    // phase 2 (M2): prev reg 6,7 (slots 4,5); CZ; next lane 0..5 + reg 6,7
    reg_gate<1>(ar, ai, sU[4]);
    reg_gate<2>(ar, ai, sU[5]);
#pragma unroll
    for (int r = 0; r < 4; ++r)
        if (cz_neg(gidx_f(Lm2[r], g, setB))) { ar[r] = -ar[r]; ai[r] = -ai[r]; }
    lane_gate(ar, ai, sU[8],  lane, 0);
    lane_gate(ar, ai, sU[9],  lane, 1);
    lane_gate(ar, ai, sU[10], lane, 2);
    lane_gate(ar, ai, sU[11], lane, 3);
    lane_gate(ar, ai, sU[12], lane, 4);
    lane_gate(ar, ai, sU[13], lane, 5);
    reg_gate<1>(ar, ai, sU[14]);
    reg_gate<2>(ar, ai, sU[15]);
    // rotate M2 -> M1 (each slot last touched by its own thread: no pre-barrier)
#pragma unroll
    for (int r = 0; r < 4; ++r) { sre[Lm2[r]] = ar[r]; sim[Lm2[r]] = ai[r]; }
    __syncthreads();
#pragma unroll
    for (int r = 0; r < 4; ++r) { ar[r] = sre[Lm1[r]]; ai[r] = sim[Lm1[r]]; }
    // phase 3 (M1): next reg 8,9 (slots 16,17), store
    reg_gate<1>(ar, ai, sU[16]);
    reg_gate<2>(ar, ai, sU[17]);
#pragma unroll
    for (int r = 0; r < 4; ++r)
        st[gidx_f(Lm1[r], g, setB)] = make_float2(ar[r], ai[r]);
}

// ---------------- K6: 8x RX(th1-th2) on psi1, dot with raw psi2 ------------
__global__ __launch_bounds__(TPB) void k6_kernel(
    const float2* __restrict__ states,
    const float* __restrict__ x1, const float* __restrict__ x2,
    const float* __restrict__ iscale,
    double* __restrict__ acc, unsigned* __restrict__ cnt,
    float* __restrict__ out)
{
    __shared__ double2 ssc8[8];
    __shared__ float2 sU[8][4];   // slot j: RX(delta) on local bit 2+j (q = 15-j)
    __shared__ float sre[NL], sim[NL];
    __shared__ double wr[4], wi[4];
    int g = blockIdx.x;
    int t = threadIdx.x, lane = t & 63, wave = t >> 6;
    const float2* s1 = states;
    const float2* s2 = states + NSTATE;

    int Lm1[4], Lm2[4];
#pragma unroll
    for (int r = 0; r < 4; ++r) {
        Lm1[r] = (r << 8) | (wave << 6) | lane;
        Lm2[r] = (wave << 8) | (r << 6) | lane;
    }
    float2 v1[4], v2[4];
#pragma unroll
    for (int r = 0; r < 4; ++r) {
        v1[r] = s1[(g << 10) | Lm1[r]];
        v2[r] = s2[(g << 10) | Lm2[r]];
    }

    if (t < 8) {
        int q = 15 - t;
        double d = (double)iscale[5 * NQ + q] * ((double)x1[q] - (double)x2[q]);
        double sn, cs;
        sincos(d * 0.5, &sn, &cs);
        ssc8[t] = make_double2(cs, sn);
    }
    __syncthreads();
    if (t < 8) {
        float c = (float)ssc8[t].x, s = (float)ssc8[t].y;
        sU[t][0] = make_float2(c, 0.f);  sU[t][1] = make_float2(0.f, -s);
        sU[t][2] = make_float2(0.f, -s); sU[t][3] = make_float2(c, 0.f);
    }
    __syncthreads();

    float ar[4], ai[4];
#pragma unroll
    for (int r = 0; r < 4; ++r) { ar[r] = v1[r].x; ai[r] = v1[r].y; }
    // phase 1 (M1): lane 2..5 (slots 0..3), reg 8,9 (slots 6,7)
    lane_gate(ar, ai, sU[0], lane, 2);
    lane_gate(ar, ai, sU[1], lane, 3);
    lane_gate(ar, ai, sU[2], lane, 4);
    lane_gate(ar, ai, sU[3], lane, 5);
    reg_gate<1>(ar, ai, sU[6]);
    reg_gate<2>(ar, ai, sU[7]);
    // rotate M1 -> M2
#pragma unroll
    for (int r = 0; r < 4; ++r) { sre[Lm1[r]] = ar[r]; sim[Lm1[r]] = ai[r]; }
    __syncthreads();
#pragma unroll
    for (int r = 0; r < 4; ++r) { ar[r] = sre[Lm2[r]]; ai[r] = sim[Lm2[r]]; }
    // phase 2 (M2): reg 6,7 (slots 4,5); dot conj(psi2) * (R psi1)
    reg_gate<1>(ar, ai, sU[4]);
    reg_gate<2>(ar, ai, sU[5]);
    double accr = 0.0, acci = 0.0;
#pragma unroll
    for (int r = 0; r < 4; ++r) {
        accr += (double)v2[r].x * ar[r] + (double)v2[r].y * ai[r];
        acci += (double)v2[r].x * ai[r] - (double)v2[r].y * ar[r];
    }
    for (int o = 32; o > 0; o >>= 1) {
        accr += __shfl_down(accr, o, 64);
        acci += __shfl_down(acci, o, 64);
    }
    if (lane == 0) { wr[wave] = accr; wi[wave] = acci; }
    __syncthreads();
    if (t == 0) {
        double br = wr[0] + wr[1] + wr[2] + wr[3];
        double bi = wi[0] + wi[1] + wi[2] + wi[3];
        atomicAdd(&acc[0], br);
        atomicAdd(&acc[1], bi);
        __threadfence();
        unsigned old = atomicAdd(cnt, 1u);
        if (old == gridDim.x - 1) {
            double fr = atomicAdd(&acc[0], 0.0);
            double fi = atomicAdd(&acc[1], 0.0);
            out[0] = (float)(fr * fr + fi * fi);
        }
    }
}

// ---------------- launch ----------------------------------------------------
extern "C" void kernel_launch(void* const* d_in, const int* in_sizes, int n_in,
                              void* d_out, int out_size, void* d_ws, size_t ws_size,
                              hipStream_t stream)
{
    const float* x1 = (const float*)d_in[0];
    const float* x2 = (const float*)d_in[1];
    const float* iscale = (const float*)d_in[2];
    const float* var = (const float*)d_in[3];
    float* out = (float*)d_out;

    // ws layout: [8192,8208) acc; [8208,8212) cnt; [16384,+4MB) statevectors
    double*   acc    = (double*)((char*)d_ws + 8192);
    unsigned* cnt    = (unsigned*)((char*)d_ws + 8208);
    float2*   states = (float2*)((char*)d_ws + 16384);

    dim3 grid(2 * NCHUNK), block(TPB);
    k1_kernel<<<grid, block, 0, stream>>>(states, x1, x2, iscale, var, acc, cnt);
    pass_kernel<<<grid, block, 0, stream>>>(states, x1, x2, iscale, var, 0, 1, 2);
    pass_kernel<<<grid, block, 0, stream>>>(states, x1, x2, iscale, var, 1, 2, 3);
    pass_kernel<<<grid, block, 0, stream>>>(states, x1, x2, iscale, var, 0, 3, 4);
    pass_kernel<<<grid, block, 0, stream>>>(states, x1, x2, iscale, var, 1, 4, 5);
    k6_kernel<<<NCHUNK, block, 0, stream>>>(states, x1, x2, iscale, acc, cnt, out);
}